// Round 11
// baseline (553.787 us; speedup 1.0000x reference)
//
#include <hip/hip_runtime.h>

#define NN 100000
#define NE 1600000
#define DF 32
#define KIT 5
#define MU 0.01f
#define NSLOT 256
#define NV4 (NN * DF / 4)

#define SCAN_CHUNK 1024
#define SCAN_NB ((NN + SCAN_CHUNK - 1) / SCAN_CHUNK)  // 98 blocks

#define BROWS 512
#define NBUCKET ((NN + BROWS - 1) / BROWS)            // 196
#define NSHARD 64
#define SC (NBUCKET * NSHARD)                          // 12544 cursors

// ---------- one-time CSR build (row is iteration-invariant) ----------

__global__ __launch_bounds__(256) void zero_kernel(int* __restrict__ p, int n) {
    int i = blockIdx.x * blockDim.x + threadIdx.x;
    if (i < n) p[i] = 0;
}

__global__ __launch_bounds__(256) void hist_kernel(const int* __restrict__ row,
                                                   int* __restrict__ deg) {
    int e = blockIdx.x * blockDim.x + threadIdx.x;
    if (e < NE) atomicAdd(&deg[row[e]], 1);
}

// per-(bucket,shard) histogram; shard = blockIdx&63 (same mapping as append)
__global__ __launch_bounds__(256) void hist2_kernel(const int* __restrict__ row,
                                                    int* __restrict__ cnt2) {
    int e = blockIdx.x * blockDim.x + threadIdx.x;
    if (e < NE) {
        const int b = row[e] >> 9;
        atomicAdd(&cnt2[b * NSHARD + (blockIdx.x & (NSHARD - 1))], 1);
    }
}

__global__ __launch_bounds__(256) void blocksum_kernel(const int* __restrict__ deg,
                                                       int* __restrict__ bsum) {
    const int t = threadIdx.x;
    const int base = blockIdx.x * SCAN_CHUNK + t * 4;
    int s = 0;
    #pragma unroll
    for (int i = 0; i < 4; ++i) {
        int idx = base + i;
        if (idx < NN) s += deg[idx];
    }
    #pragma unroll
    for (int m = 32; m > 0; m >>= 1) s += __shfl_xor(s, m, 64);
    __shared__ int sm[4];
    if ((t & 63) == 0) sm[t >> 6] = s;
    __syncthreads();
    if (t == 0) bsum[blockIdx.x] = sm[0] + sm[1] + sm[2] + sm[3];
}

__global__ __launch_bounds__(128) void scanbsum_kernel(int* __restrict__ bsum) {
    __shared__ int sh[SCAN_NB];
    const int t = threadIdx.x;
    if (t < SCAN_NB) sh[t] = bsum[t];
    __syncthreads();
    if (t == 0) {
        int run = 0;
        for (int i = 0; i < SCAN_NB; ++i) {
            int v = sh[i];
            sh[i] = run;
            run += v;
        }
    }
    __syncthreads();
    if (t < SCAN_NB) bsum[t] = sh[t];
}

__global__ __launch_bounds__(256) void scanfinal_kernel(const int* __restrict__ deg,
                                                        const int* __restrict__ bsum,
                                                        int* __restrict__ rowptr) {
    const int t = threadIdx.x;
    const int base = blockIdx.x * SCAN_CHUNK + t * 4;
    int d[4];
    int s = 0;
    #pragma unroll
    for (int i = 0; i < 4; ++i) {
        int idx = base + i;
        d[i] = (idx < NN) ? deg[idx] : 0;
        s += d[i];
    }
    __shared__ int sh[256];
    sh[t] = s;
    __syncthreads();
    for (int off = 1; off < 256; off <<= 1) {
        int v = (t >= off) ? sh[t - off] : 0;
        __syncthreads();
        sh[t] += v;
        __syncthreads();
    }
    int run = bsum[blockIdx.x] + sh[t] - s;
    #pragma unroll
    for (int i = 0; i < 4; ++i) {
        int idx = base + i;
        if (idx < NN) {
            rowptr[idx] = run;
            run += d[i];
        }
    }
    if (blockIdx.x == 0 && t == 0) rowptr[NN] = NE;
}

// per-bucket exclusive scan over 64 shard counts -> cur2 append cursors
__global__ __launch_bounds__(64) void shardscan_kernel(const int* __restrict__ cnt2,
                                                       const int* __restrict__ rowptr,
                                                       int* __restrict__ cur2) {
    const int b = blockIdx.x;
    const int t = threadIdx.x;  // 0..63
    const int v = cnt2[b * NSHARD + t];
    int inc = v;
    #pragma unroll
    for (int off = 1; off < 64; off <<= 1) {
        int w = __shfl_up(inc, off, 64);
        if (t >= off) inc += w;
    }
    cur2[b * NSHARD + t] = rowptr[b * BROWS] + inc - v;
}

// append pass: sequential writes per (bucket,shard) region -> no write thrash
__global__ __launch_bounds__(256) void append_kernel(const int* __restrict__ row,
                                                     const int* __restrict__ col,
                                                     int* __restrict__ cur2,
                                                     unsigned int* __restrict__ packed) {
    int e = blockIdx.x * blockDim.x + threadIdx.x;
    if (e < NE) {
        const int r = row[e];
        const int b = r >> 9;
        const int pos = atomicAdd(&cur2[b * NSHARD + (blockIdx.x & (NSHARD - 1))], 1);
        packed[pos] = ((unsigned int)(r & (BROWS - 1)) << 17) | (unsigned int)col[e];
    }
}

// one WG per bucket: scatter cols within the 32KB L2-resident segment
__global__ __launch_bounds__(256) void bucket_sort_kernel(const int* __restrict__ rowptr,
                                                          const unsigned int* __restrict__ packed,
                                                          int* __restrict__ colsorted) {
    const int b = blockIdx.x;
    const int base = b * BROWS;
    const int rows = min(BROWS, NN - base);
    const int segbase = rowptr[base];
    const int segend = rowptr[base + rows];
    __shared__ int cur[BROWS];
    for (int i = threadIdx.x; i < rows; i += 256) cur[i] = rowptr[base + i] - segbase;
    __syncthreads();
    for (int j = segbase + threadIdx.x; j < segend; j += 256) {
        const unsigned int p = packed[j];
        const int rl = p >> 17;
        const int c = (int)(p & 0x1FFFFu);
        const int pos = atomicAdd(&cur[rl], 1);
        colsorted[segbase + pos] = c;
    }
}

// ---------- bf16 shadow helpers ----------

__device__ __forceinline__ unsigned int pack2bf(float a, float b) {
    unsigned int ua = __float_as_uint(a);
    unsigned int ub = __float_as_uint(b);
    return ((ua + 0x8000u) >> 16) | (((ub + 0x8000u) >> 16) << 16);
}

__device__ __forceinline__ void unpack8(uint4 v, float* f) {
    f[0] = __uint_as_float(v.x << 16);
    f[1] = __uint_as_float(v.x & 0xffff0000u);
    f[2] = __uint_as_float(v.y << 16);
    f[3] = __uint_as_float(v.y & 0xffff0000u);
    f[4] = __uint_as_float(v.z << 16);
    f[5] = __uint_as_float(v.z & 0xffff0000u);
    f[6] = __uint_as_float(v.w << 16);
    f[7] = __uint_as_float(v.w & 0xffff0000u);
}

__global__ __launch_bounds__(256) void tobf16_kernel(const float4* __restrict__ h,
                                                     uint2* __restrict__ hb) {
    int i = blockIdx.x * blockDim.x + threadIdx.x;
    if (i < NV4) {
        const float4 v = h[i];
        hb[i] = make_uint2(pack2bf(v.x, v.y), pack2bf(v.z, v.w));
    }
}

// ---------- per-iteration ----------

// One 32-lane group per 4 NODES. lane = q(3b)*4 + f2(2b); a lane-quad covers
// one 64B bf16 row (uint4/lane). All 24 loads (4 col vectors, 4 own rows,
// 16 batch gathers) issued before any consumption -> ~24 vmem in flight.
// First 32 edges of each node via one batch; deg>32 tail loops (rare).
__global__ __launch_bounds__(256) void agg_kernel(const uint4* __restrict__ hb4,
                                                  const int* __restrict__ rowptr,
                                                  const int* __restrict__ colsorted,
                                                  float* __restrict__ S,
                                                  int* __restrict__ maxslots) {
    const int lane = threadIdx.x & 31;
    const int q = lane >> 2;
    const int f2 = lane & 3;
    const int g = (blockIdx.x * blockDim.x + threadIdx.x) >> 5;
    const int n0 = g * 4;

    int rp[5];
    #pragma unroll
    for (int i = 0; i < 5; ++i) rp[i] = rowptr[n0 + i];

    // head col loads (coalesced, lane-indexed)
    int cidx[4];
    #pragma unroll
    for (int i = 0; i < 4; ++i) {
        const int idx = rp[i] + lane;
        cidx[i] = (idx < rp[i + 1]) ? colsorted[idx] : (n0 + i);
    }
    // own rows
    uint4 hru[4];
    #pragma unroll
    for (int i = 0; i < 4; ++i) hru[i] = hb4[(n0 + i) * 4 + f2];
    // 16 batch gathers, all issued back-to-back
    uint4 u[4][4];
    #pragma unroll
    for (int i = 0; i < 4; ++i) {
        #pragma unroll
        for (int j = 0; j < 4; ++j) {
            u[i][j] = hb4[__shfl(cidx[i], 8 * j + q, 32) * 4 + f2];
        }
    }

    float accs[4][8];
    #pragma unroll
    for (int i = 0; i < 4; ++i)
        #pragma unroll
        for (int k = 0; k < 8; ++k) accs[i][k] = 0.0f;
    float nmax = 0.0f;

    #pragma unroll
    for (int i = 0; i < 4; ++i) {
        float hr[8];
        unpack8(hru[i], hr);
        #pragma unroll
        for (int j = 0; j < 4; ++j) {
            float d[8];
            unpack8(u[i][j], d);
            float s = 0.0f;
            #pragma unroll
            for (int k = 0; k < 8; ++k) {
                d[k] = hr[k] - d[k];
                s = fmaf(d[k], d[k], s);
            }
            s += __shfl_xor(s, 1, 32);
            s += __shfl_xor(s, 2, 32);
            const float n = fmaxf(sqrtf(s), 1e-6f);
            nmax = fmaxf(nmax, n);
            const float w = rsqrtf(n);
            #pragma unroll
            for (int k = 0; k < 8; ++k) accs[i][k] = fmaf(-d[k], w, accs[i][k]);
        }
        // rare tail (deg > 32)
        for (int kk = rp[i] + 32; kk < rp[i + 1]; kk += 8) {
            const int ei = kk + q;
            const int c = (ei < rp[i + 1]) ? colsorted[ei] : (n0 + i);
            const uint4 uu = hb4[c * 4 + f2];
            float d[8];
            unpack8(uu, d);
            float s = 0.0f;
            #pragma unroll
            for (int k = 0; k < 8; ++k) {
                d[k] = hr[k] - d[k];
                s = fmaf(d[k], d[k], s);
            }
            s += __shfl_xor(s, 1, 32);
            s += __shfl_xor(s, 2, 32);
            const float n = fmaxf(sqrtf(s), 1e-6f);
            nmax = fmaxf(nmax, n);
            const float w = rsqrtf(n);
            #pragma unroll
            for (int k = 0; k < 8; ++k) accs[i][k] = fmaf(-d[k], w, accs[i][k]);
        }
    }

    // cross-quad reduce (quads hold different edges, same feats)
    #pragma unroll
    for (int m = 4; m < 32; m <<= 1) {
        #pragma unroll
        for (int i = 0; i < 4; ++i)
            #pragma unroll
            for (int k = 0; k < 8; ++k) accs[i][k] += __shfl_xor(accs[i][k], m, 32);
    }
    if (q == 0) {
        #pragma unroll
        for (int i = 0; i < 4; ++i) {
            ((float4*)S)[(n0 + i) * 8 + f2 * 2] =
                make_float4(accs[i][0], accs[i][1], accs[i][2], accs[i][3]);
            ((float4*)S)[(n0 + i) * 8 + f2 * 2 + 1] =
                make_float4(accs[i][4], accs[i][5], accs[i][6], accs[i][7]);
        }
    }

    // group max -> wave max -> spread atomic
    nmax = fmaxf(nmax, __shfl_xor(nmax, 4, 32));
    nmax = fmaxf(nmax, __shfl_xor(nmax, 8, 32));
    nmax = fmaxf(nmax, __shfl_xor(nmax, 16, 32));
    nmax = fmaxf(nmax, __shfl_xor(nmax, 32, 64));
    if ((threadIdx.x & 63) == 0) {
        // positive floats order like ints; 0xAA poison is negative -> loses
        atomicMax(&maxslots[blockIdx.x & (NSLOT - 1)], __float_as_int(nmax));
    }
}

// h_out = h_in - MU*sqrt(M)*S (fp32), plus refresh of the bf16 shadow.
__global__ __launch_bounds__(256) void update_kernel(const float4* __restrict__ hcur,
                                                     float4* __restrict__ hnxt,
                                                     uint2* __restrict__ hb,
                                                     const float4* __restrict__ S,
                                                     const int* __restrict__ slots) {
    const int t = threadIdx.x;
    int v = slots[t];
    #pragma unroll
    for (int m = 32; m > 0; m >>= 1) v = max(v, __shfl_xor(v, m, 64));
    __shared__ int sm[4];
    __shared__ float sscale;
    if ((t & 63) == 0) sm[t >> 6] = v;
    __syncthreads();
    if (t == 0) {
        int bm = max(max(sm[0], sm[1]), max(sm[2], sm[3]));
        sscale = MU * sqrtf(__int_as_float(bm));
    }
    __syncthreads();
    const float scale = sscale;
    const int i = blockIdx.x * blockDim.x + t;
    if (i < NV4) {
        const float4 hv = hcur[i];
        const float4 sv = S[i];
        float4 o;
        o.x = hv.x - scale * sv.x;
        o.y = hv.y - scale * sv.y;
        o.z = hv.z - scale * sv.z;
        o.w = hv.w - scale * sv.w;
        hnxt[i] = o;
        hb[i] = make_uint2(pack2bf(o.x, o.y), pack2bf(o.z, o.w));
    }
}

extern "C" void kernel_launch(void* const* d_in, const int* in_sizes, int n_in,
                              void* d_out, int out_size, void* d_ws, size_t ws_size,
                              hipStream_t stream) {
    const float* h_in = (const float*)d_in[0];
    const int* row = (const int*)d_in[1];
    const int* col = row + NE;
    float* out = (float*)d_out;

    float* S = (float*)d_ws;                        // NN*DF f32
    int* maxslots = (int*)(S + NN * DF);            // KIT*NSLOT
    int* deg = maxslots + KIT * NSLOT;              // NN   (contiguous with cnt2
    int* cnt2 = deg + NN;                           // SC    for one zero pass)
    int* rowptr = cnt2 + SC;                        // NN+1
    int* bsum = rowptr + NN + 1;                    // SCAN_NB
    int* cur2 = bsum + SCAN_NB;                     // SC
    unsigned int* packed = (unsigned int*)(cur2 + SC);  // NE
    int* colsorted = (int*)(packed + NE);           // NE
    uintptr_t p = (uintptr_t)(colsorted + NE);
    p = (p + 15) & ~(uintptr_t)15;
    uint2* hb = (uint2*)p;                          // NN*DF bf16 = 6.4 MB

    const int eb = (NE + 255) / 256;                // 6250
    const int zb = (NN + SC + 255) / 256;
    const int gb = (NN / 4 * 32 + 255) / 256;       // 3125
    const int ub = (NV4 + 255) / 256;               // 3125

    zero_kernel<<<zb, 256, 0, stream>>>(deg, NN + SC);   // deg + cnt2
    hist_kernel<<<eb, 256, 0, stream>>>(row, deg);
    hist2_kernel<<<eb, 256, 0, stream>>>(row, cnt2);
    blocksum_kernel<<<SCAN_NB, 256, 0, stream>>>(deg, bsum);
    scanbsum_kernel<<<1, 128, 0, stream>>>(bsum);
    scanfinal_kernel<<<SCAN_NB, 256, 0, stream>>>(deg, bsum, rowptr);
    shardscan_kernel<<<NBUCKET, 64, 0, stream>>>(cnt2, rowptr, cur2);
    append_kernel<<<eb, 256, 0, stream>>>(row, col, cur2, packed);
    bucket_sort_kernel<<<NBUCKET, 256, 0, stream>>>(rowptr, packed, colsorted);
    tobf16_kernel<<<ub, 256, 0, stream>>>((const float4*)h_in, hb);

    for (int it = 0; it < KIT; ++it) {
        const float* cur = (it == 0) ? h_in : out;
        agg_kernel<<<gb, 256, 0, stream>>>((const uint4*)hb, rowptr, colsorted, S,
                                           maxslots + it * NSLOT);
        update_kernel<<<ub, 256, 0, stream>>>((const float4*)cur, (float4*)out, hb,
                                              (const float4*)S,
                                              maxslots + it * NSLOT);
    }
}

// Round 12
// 458.768 us; speedup vs baseline: 1.2071x; 1.2071x over previous
//
#include <hip/hip_runtime.h>

#define NN 100000
#define NE 1600000
#define DF 32
#define KIT 5
#define MU 0.01f
#define NSLOT 256
#define NV4 (NN * DF / 4)
#define ELLW 36
#define AUXCAP 65536

// ---------- one-time ELL build (edge_index is iteration-invariant) ----------

__global__ __launch_bounds__(256) void zero_kernel(int* __restrict__ p, int n) {
    int i = blockIdx.x * blockDim.x + threadIdx.x;
    if (i < n) p[i] = 0;
}

// degc[r] counts edges (atomic return value = ELL slot). Slots >= ELLW go to
// the aux overflow list (a.s. empty at Poisson(16), but guarantees correctness).
__global__ __launch_bounds__(256) void ell_fill_kernel(const int* __restrict__ row,
                                                       const int* __restrict__ col,
                                                       int* __restrict__ degc,
                                                       int* __restrict__ colell,
                                                       int* __restrict__ auxcnt,
                                                       int2* __restrict__ aux) {
    int e = blockIdx.x * blockDim.x + threadIdx.x;
    if (e < NE) {
        const int r = row[e];
        const int c = col[e];
        const int pos = atomicAdd(&degc[r], 1);
        if (pos < ELLW) {
            colell[r * ELLW + pos] = c;
        } else {
            const int a = atomicAdd(auxcnt, 1);
            if (a < AUXCAP) aux[a] = make_int2(r, c);
        }
    }
}

// ---------- bf16 shadow helpers ----------

__device__ __forceinline__ unsigned int pack2bf(float a, float b) {
    unsigned int ua = __float_as_uint(a);
    unsigned int ub = __float_as_uint(b);
    return ((ua + 0x8000u) >> 16) | (((ub + 0x8000u) >> 16) << 16);
}

__device__ __forceinline__ void unpack8(uint4 v, float* f) {
    f[0] = __uint_as_float(v.x << 16);
    f[1] = __uint_as_float(v.x & 0xffff0000u);
    f[2] = __uint_as_float(v.y << 16);
    f[3] = __uint_as_float(v.y & 0xffff0000u);
    f[4] = __uint_as_float(v.z << 16);
    f[5] = __uint_as_float(v.z & 0xffff0000u);
    f[6] = __uint_as_float(v.w << 16);
    f[7] = __uint_as_float(v.w & 0xffff0000u);
}

__global__ __launch_bounds__(256) void tobf16_kernel(const float4* __restrict__ h,
                                                     uint2* __restrict__ hb) {
    int i = blockIdx.x * blockDim.x + threadIdx.x;
    if (i < NV4) {
        const float4 v = h[i];
        hb[i] = make_uint2(pack2bf(v.x, v.y), pack2bf(v.z, v.w));
    }
}

// ---------- per-iteration ----------

// One 32-lane group per NODE PAIR (R10-proven shape). lane = q(3b)*4 + f2(2b);
// a lane-quad covers one 64B bf16 row (uint4/lane). All 10 loads (2 ELL col
// vectors, 2 own rows, 8 batch gathers) issued before any consumption.
// First 32 edges per node in one batch; edges 32..deg-1 (deg<=36) in one
// guarded tail step. Invalid slots gather the node's own row (d==0 exactly).
__global__ __launch_bounds__(256) void agg_kernel(const uint4* __restrict__ hb4,
                                                  const int* __restrict__ degc,
                                                  const int* __restrict__ colell,
                                                  float* __restrict__ S,
                                                  int* __restrict__ maxslots) {
    const int lane = threadIdx.x & 31;
    const int q = lane >> 2;
    const int f2 = lane & 3;
    const int pair = (blockIdx.x * blockDim.x + threadIdx.x) >> 5;
    const int n0 = pair * 2;
    const int n1 = n0 + 1;

    const int d0 = min(degc[n0], ELLW);
    const int d1 = min(degc[n1], ELLW);

    // head loads, all independent
    const int ca = (lane < d0) ? colell[n0 * ELLW + lane] : n0;
    const int cb = (lane < d1) ? colell[n1 * ELLW + lane] : n1;
    const uint4 hru0 = hb4[n0 * 4 + f2];
    const uint4 hru1 = hb4[n1 * 4 + f2];

    uint4 u0[4], u1[4];
    #pragma unroll
    for (int j = 0; j < 4; ++j) u0[j] = hb4[__shfl(ca, 8 * j + q, 32) * 4 + f2];
    #pragma unroll
    for (int j = 0; j < 4; ++j) u1[j] = hb4[__shfl(cb, 8 * j + q, 32) * 4 + f2];

    float hr0[8], hr1[8];
    unpack8(hru0, hr0);
    unpack8(hru1, hr1);

    float acc0[8], acc1[8];
    #pragma unroll
    for (int i = 0; i < 8; ++i) { acc0[i] = 0.0f; acc1[i] = 0.0f; }
    float nmax = 0.0f;

    #pragma unroll
    for (int j = 0; j < 4; ++j) {
        float d[8];
        unpack8(u0[j], d);
        float s = 0.0f;
        #pragma unroll
        for (int i = 0; i < 8; ++i) {
            d[i] = hr0[i] - d[i];
            s = fmaf(d[i], d[i], s);
        }
        s += __shfl_xor(s, 1, 32);
        s += __shfl_xor(s, 2, 32);
        const float n = fmaxf(sqrtf(s), 1e-6f);
        nmax = fmaxf(nmax, n);
        const float w = rsqrtf(n);
        #pragma unroll
        for (int i = 0; i < 8; ++i) acc0[i] = fmaf(-d[i], w, acc0[i]);
    }
    #pragma unroll
    for (int j = 0; j < 4; ++j) {
        float d[8];
        unpack8(u1[j], d);
        float s = 0.0f;
        #pragma unroll
        for (int i = 0; i < 8; ++i) {
            d[i] = hr1[i] - d[i];
            s = fmaf(d[i], d[i], s);
        }
        s += __shfl_xor(s, 1, 32);
        s += __shfl_xor(s, 2, 32);
        const float n = fmaxf(sqrtf(s), 1e-6f);
        nmax = fmaxf(nmax, n);
        const float w = rsqrtf(n);
        #pragma unroll
        for (int i = 0; i < 8; ++i) acc1[i] = fmaf(-d[i], w, acc1[i]);
    }

    // tails: edges 32..d-1 (at most one 8-edge step since ELLW=36)
    for (int k = 32; k < d0; k += 8) {
        const int ei = k + q;
        const int c = (ei < d0) ? colell[n0 * ELLW + ei] : n0;
        const uint4 uu = hb4[c * 4 + f2];
        float d[8];
        unpack8(uu, d);
        float s = 0.0f;
        #pragma unroll
        for (int i = 0; i < 8; ++i) {
            d[i] = hr0[i] - d[i];
            s = fmaf(d[i], d[i], s);
        }
        s += __shfl_xor(s, 1, 32);
        s += __shfl_xor(s, 2, 32);
        const float n = fmaxf(sqrtf(s), 1e-6f);
        nmax = fmaxf(nmax, n);
        const float w = rsqrtf(n);
        #pragma unroll
        for (int i = 0; i < 8; ++i) acc0[i] = fmaf(-d[i], w, acc0[i]);
    }
    for (int k = 32; k < d1; k += 8) {
        const int ei = k + q;
        const int c = (ei < d1) ? colell[n1 * ELLW + ei] : n1;
        const uint4 uu = hb4[c * 4 + f2];
        float d[8];
        unpack8(uu, d);
        float s = 0.0f;
        #pragma unroll
        for (int i = 0; i < 8; ++i) {
            d[i] = hr1[i] - d[i];
            s = fmaf(d[i], d[i], s);
        }
        s += __shfl_xor(s, 1, 32);
        s += __shfl_xor(s, 2, 32);
        const float n = fmaxf(sqrtf(s), 1e-6f);
        nmax = fmaxf(nmax, n);
        const float w = rsqrtf(n);
        #pragma unroll
        for (int i = 0; i < 8; ++i) acc1[i] = fmaf(-d[i], w, acc1[i]);
    }

    // cross-quad reduce (quads hold different edges, same feats)
    #pragma unroll
    for (int m = 4; m < 32; m <<= 1) {
        #pragma unroll
        for (int i = 0; i < 8; ++i) {
            acc0[i] += __shfl_xor(acc0[i], m, 32);
            acc1[i] += __shfl_xor(acc1[i], m, 32);
        }
    }
    if (q == 0) {
        ((float4*)S)[n0 * 8 + f2 * 2] = make_float4(acc0[0], acc0[1], acc0[2], acc0[3]);
        ((float4*)S)[n0 * 8 + f2 * 2 + 1] = make_float4(acc0[4], acc0[5], acc0[6], acc0[7]);
        ((float4*)S)[n1 * 8 + f2 * 2] = make_float4(acc1[0], acc1[1], acc1[2], acc1[3]);
        ((float4*)S)[n1 * 8 + f2 * 2 + 1] = make_float4(acc1[4], acc1[5], acc1[6], acc1[7]);
    }

    nmax = fmaxf(nmax, __shfl_xor(nmax, 4, 32));
    nmax = fmaxf(nmax, __shfl_xor(nmax, 8, 32));
    nmax = fmaxf(nmax, __shfl_xor(nmax, 16, 32));
    nmax = fmaxf(nmax, __shfl_xor(nmax, 32, 64));
    if ((threadIdx.x & 63) == 0) {
        // positive floats order like ints; 0xAA poison is negative -> loses
        atomicMax(&maxslots[blockIdx.x & (NSLOT - 1)], __float_as_int(nmax));
    }
}

// overflow edges (deg > ELLW): full per-edge norm + atomic accumulate into S.
// Almost surely empty; grid-stride guarantees coverage. Runs AFTER agg (its
// plain S stores) and BEFORE update.
__global__ __launch_bounds__(256) void aux_kernel(const uint2* __restrict__ hb,
                                                  const int2* __restrict__ aux,
                                                  const int* __restrict__ auxcnt,
                                                  float* __restrict__ S,
                                                  int* __restrict__ maxslots) {
    const int n = min(*auxcnt, AUXCAP);
    for (int i = blockIdx.x * blockDim.x + threadIdx.x; i < n;
         i += gridDim.x * blockDim.x) {
        const int r = aux[i].x;
        const int c = aux[i].y;
        float d[32];
        float s = 0.0f;
        for (int j = 0; j < 8; ++j) {
            const uint2 ur = hb[r * 8 + j];
            const uint2 uc = hb[c * 8 + j];
            float fr[4], fc[4];
            fr[0] = __uint_as_float(ur.x << 16);
            fr[1] = __uint_as_float(ur.x & 0xffff0000u);
            fr[2] = __uint_as_float(ur.y << 16);
            fr[3] = __uint_as_float(ur.y & 0xffff0000u);
            fc[0] = __uint_as_float(uc.x << 16);
            fc[1] = __uint_as_float(uc.x & 0xffff0000u);
            fc[2] = __uint_as_float(uc.y << 16);
            fc[3] = __uint_as_float(uc.y & 0xffff0000u);
            #pragma unroll
            for (int k = 0; k < 4; ++k) {
                d[j * 4 + k] = fr[k] - fc[k];
                s = fmaf(d[j * 4 + k], d[j * 4 + k], s);
            }
        }
        const float nn = fmaxf(sqrtf(s), 1e-6f);
        atomicMax(&maxslots[i & (NSLOT - 1)], __float_as_int(nn));
        const float w = rsqrtf(nn);
        for (int f = 0; f < 32; ++f) atomicAdd(&S[r * DF + f], -d[f] * w);
    }
}

// h_out = h_in - MU*sqrt(M)*S (fp32), plus refresh of the bf16 shadow.
__global__ __launch_bounds__(256) void update_kernel(const float4* __restrict__ hcur,
                                                     float4* __restrict__ hnxt,
                                                     uint2* __restrict__ hb,
                                                     const float4* __restrict__ S,
                                                     const int* __restrict__ slots) {
    const int t = threadIdx.x;
    int v = slots[t];
    #pragma unroll
    for (int m = 32; m > 0; m >>= 1) v = max(v, __shfl_xor(v, m, 64));
    __shared__ int sm[4];
    __shared__ float sscale;
    if ((t & 63) == 0) sm[t >> 6] = v;
    __syncthreads();
    if (t == 0) {
        int bm = max(max(sm[0], sm[1]), max(sm[2], sm[3]));
        sscale = MU * sqrtf(__int_as_float(bm));
    }
    __syncthreads();
    const float scale = sscale;
    const int i = blockIdx.x * blockDim.x + t;
    if (i < NV4) {
        const float4 hv = hcur[i];
        const float4 sv = S[i];
        float4 o;
        o.x = hv.x - scale * sv.x;
        o.y = hv.y - scale * sv.y;
        o.z = hv.z - scale * sv.z;
        o.w = hv.w - scale * sv.w;
        hnxt[i] = o;
        hb[i] = make_uint2(pack2bf(o.x, o.y), pack2bf(o.z, o.w));
    }
}

extern "C" void kernel_launch(void* const* d_in, const int* in_sizes, int n_in,
                              void* d_out, int out_size, void* d_ws, size_t ws_size,
                              hipStream_t stream) {
    const float* h_in = (const float*)d_in[0];
    const int* row = (const int*)d_in[1];
    const int* col = row + NE;
    float* out = (float*)d_out;

    float* S = (float*)d_ws;                         // NN*DF f32   (12.8 MB)
    int* maxslots = (int*)(S + NN * DF);             // KIT*NSLOT
    int* degc = maxslots + KIT * NSLOT;              // NN
    int* auxcnt = degc + NN;                         // 1 (contiguous with degc)
    uintptr_t pa = (uintptr_t)(auxcnt + 1);
    pa = (pa + 7) & ~(uintptr_t)7;
    int2* aux = (int2*)pa;                           // AUXCAP      (0.5 MB)
    int* colell = (int*)(aux + AUXCAP);              // NN*ELLW     (14.4 MB)
    uintptr_t p = (uintptr_t)(colell + NN * ELLW);
    p = (p + 15) & ~(uintptr_t)15;
    uint2* hb = (uint2*)p;                           // NN*DF bf16  (6.4 MB)

    const int eb = (NE + 255) / 256;                 // 6250
    const int zb = (NN + 1 + 255) / 256;
    const int gb = (NN / 2 * 32 + 255) / 256;        // 6250
    const int ub = (NV4 + 255) / 256;                // 3125

    zero_kernel<<<zb, 256, 0, stream>>>(degc, NN + 1);   // degc + auxcnt
    ell_fill_kernel<<<eb, 256, 0, stream>>>(row, col, degc, colell, auxcnt, aux);
    tobf16_kernel<<<ub, 256, 0, stream>>>((const float4*)h_in, hb);

    for (int it = 0; it < KIT; ++it) {
        const float* cur = (it == 0) ? h_in : out;
        agg_kernel<<<gb, 256, 0, stream>>>((const uint4*)hb, degc, colell, S,
                                           maxslots + it * NSLOT);
        aux_kernel<<<32, 256, 0, stream>>>(hb, aux, auxcnt, S, maxslots + it * NSLOT);
        update_kernel<<<ub, 256, 0, stream>>>((const float4*)cur, (float4*)out, hb,
                                              (const float4*)S,
                                              maxslots + it * NSLOT);
    }
}